// Round 1
// baseline (1661.093 us; speedup 1.0000x reference)
//
#include <hip/hip_runtime.h>

#define STRIDE 20   // LDS row stride for [256][16] activation tiles (pad 16->20: 16B-aligned, odd-ish bank spread)
#define ASTR   17   // alpha row stride

// 4x4 grid adjacency + self loops, bitmask over source nodes j for each target i
__device__ constexpr unsigned KMASK[16] = {
  0x0013u,0x0027u,0x004Eu,0x008Cu,
  0x0131u,0x0272u,0x04E4u,0x08C8u,
  0x1310u,0x2720u,0x4E40u,0x8C80u,
  0x3100u,0x7200u,0xE400u,0xC800u};

// GEMM: dst[o][n] = sum_k src[k][n] * W[k][o]   (src/dst transposed-in-LDS [F][16])
// 256 threads: thread owns 2 consecutive cols o=2q,2q+1 and NPT=FOUT/32 nodes.
template<int FIN, int FOUT, bool BIAS_RELU>
__device__ __forceinline__ void gemm_t(const float* __restrict__ W,
                                       const float* __restrict__ bias,
                                       const float* src, float* dst, const int t){
  constexpr int NPT = FOUT / 32;           // 256 -> 8 nodes/thread, 64 -> 2
  constexpr int QM  = FOUT / 2 - 1;
  constexpr int GSH = (FOUT == 256) ? 7 : 5;
  const int q  = t & QM;
  const int g  = t >> GSH;
  const int n0 = NPT * g;                  // within a wave g is uniform -> broadcast LDS reads
  float acc0[NPT] = {}, acc1[NPT] = {};
  const float* wp = W + 2 * q;
  #pragma unroll 4
  for (int k = 0; k < FIN; ++k){
    float a[NPT];
    if constexpr (NPT == 8){
      const float4 v0 = *(const float4*)&src[k*STRIDE + n0];
      const float4 v1 = *(const float4*)&src[k*STRIDE + n0 + 4];
      a[0]=v0.x; a[1]=v0.y; a[2]=v0.z; a[3]=v0.w;
      a[4]=v1.x; a[5]=v1.y; a[6]=v1.z; a[7]=v1.w;
    } else {
      const float2 v0 = *(const float2*)&src[k*STRIDE + n0];
      a[0]=v0.x; a[1]=v0.y;
    }
    const float2 wv = *(const float2*)&wp[k*FOUT];   // coalesced, L1/L2-resident
    #pragma unroll
    for (int u = 0; u < NPT; ++u){ acc0[u] += a[u]*wv.x; acc1[u] += a[u]*wv.y; }
  }
  #pragma unroll
  for (int j = 0; j < 2; ++j){
    const float* accp = j ? acc1 : acc0;
    const int o = 2*q + j;
    float bv = 0.f;
    if constexpr (BIAS_RELU) bv = bias[o];
    float v[NPT];
    #pragma unroll
    for (int u = 0; u < NPT; ++u){
      float xv = accp[u] + bv;
      v[u] = BIAS_RELU ? fmaxf(xv, 0.f) : xv;
    }
    if constexpr (NPT == 8){
      *(float4*)&dst[o*STRIDE + n0]     = make_float4(v[0],v[1],v[2],v[3]);
      *(float4*)&dst[o*STRIDE + n0 + 4] = make_float4(v[4],v[5],v[6],v[7]);
    } else {
      *(float2*)&dst[o*STRIDE + n0]     = make_float2(v[0],v[1]);
    }
  }
}

// GAT attention stage. wave w == head w (t = h*64 + c). wh in LDS [256][STRIDE].
template<bool CONCAT>
__device__ __forceinline__ void attn_layer(const float* wh, float* outb,
    const float* __restrict__ asrc, const float* __restrict__ adst,
    const float* __restrict__ bias, float* alpha, const int t){
  const int lane = t & 63;
  const int h    = t >> 6;
  float w[16];                       // this thread's wh column o=t over all 16 nodes
  #pragma unroll
  for (int u = 0; u < 4; ++u){
    const float4 v = *(const float4*)&wh[t*STRIDE + 4*u];
    w[4*u]=v.x; w[4*u+1]=v.y; w[4*u+2]=v.z; w[4*u+3]=v.w;
  }
  const float as = asrc[t], ad = adst[t];   // asrc[h][c] with t = h*64+c
  float es[16], ed[16];
  #pragma unroll
  for (int n = 0; n < 16; ++n){ es[n] = w[n]*as; ed[n] = w[n]*ad; }
  #pragma unroll
  for (int s = 1; s < 64; s <<= 1){        // 64-lane butterfly: dot over c
    #pragma unroll
    for (int n = 0; n < 16; ++n){
      es[n] += __shfl_xor(es[n], s, 64);
      ed[n] += __shfl_xor(ed[n], s, 64);
    }
  }
  if (lane < 16){                          // lane i: softmax row i of head h
    const int i = lane;
    const unsigned m = KMASK[i];
    float mx = -1e30f;
    float ev[16];
    #pragma unroll
    for (int j = 0; j < 16; ++j){
      float e = ed[i] + es[j];
      e = e > 0.f ? e : 0.2f*e;            // leaky relu 0.2
      ev[j] = e;
      if ((m >> j) & 1u) mx = fmaxf(mx, e);
    }
    float ssum = 0.f;
    #pragma unroll
    for (int j = 0; j < 16; ++j){
      const float a = ((m >> j) & 1u) ? expf(ev[j] - mx) : 0.f;
      ev[j] = a; ssum += a;
    }
    const float inv = 1.f / ssum;
    #pragma unroll
    for (int j = 0; j < 16; ++j)
      alpha[h*(16*ASTR) + i*ASTR + j] = ev[j] * inv;
  }
  __syncthreads();
  float res[16];
  #pragma unroll
  for (int i = 0; i < 16; ++i){            // aggregation over neighbors (compile-time mask)
    float r = 0.f;
    #pragma unroll
    for (int j = 0; j < 16; ++j){
      if ((KMASK[i] >> j) & 1u)
        r += alpha[h*(16*ASTR) + i*ASTR + j] * w[j];
    }
    res[i] = r;
  }
  if constexpr (CONCAT){
    const float bv = bias[t];
    #pragma unroll
    for (int u = 0; u < 4; ++u){
      float4 v;
      v.x = fmaxf(res[4*u]   + bv, 0.f);
      v.y = fmaxf(res[4*u+1] + bv, 0.f);
      v.z = fmaxf(res[4*u+2] + bv, 0.f);
      v.w = fmaxf(res[4*u+3] + bv, 0.f);
      *(float4*)&outb[t*STRIDE + 4*u] = v;
    }
  } else {
    #pragma unroll
    for (int u = 0; u < 4; ++u){
      *(float4*)&outb[t*STRIDE + 4*u] =
        make_float4(res[4*u], res[4*u+1], res[4*u+2], res[4*u+3]);
    }
  }
}

__global__ __launch_bounds__(256, 2) void gat_fused(
  const float* __restrict__ x,   const float* __restrict__ w_in, const float* __restrict__ b_in,
  const float* __restrict__ W0,  const float* __restrict__ as0,  const float* __restrict__ ad0, const float* __restrict__ bb0,
  const float* __restrict__ W1,  const float* __restrict__ as1,  const float* __restrict__ ad1, const float* __restrict__ bb1,
  const float* __restrict__ W2,  const float* __restrict__ as2,  const float* __restrict__ ad2, const float* __restrict__ bb2,
  const float* __restrict__ w1,  const float* __restrict__ b1,
  const float* __restrict__ lng, const float* __restrict__ lnb,
  const float* __restrict__ w2,  const float* __restrict__ b2,
  float* __restrict__ out)
{
  __shared__ float bufA[256*STRIDE];
  __shared__ float bufB[256*STRIDE];
  __shared__ float alpha[4*16*ASTR];
  __shared__ float gsm[64];
  __shared__ float ylds[128];
  __shared__ float red[4];
  const int b = blockIdx.x;
  const int t = threadIdx.x;

  // grid_to_graph: h0[n][c] = x[b, c, n]; store transposed A_t[c][n] -> straight coalesced copy
  bufA[(t >> 4)*STRIDE + (t & 15)] = x[b*256 + t];
  __syncthreads();

  gemm_t<16, 64, true>(w_in, b_in, bufA, bufB, t);       // h1 = relu(h0@w_in + b_in)  [64][16]
  __syncthreads();
  gemm_t<64, 256, false>(W0, nullptr, bufB, bufA, t);    // wh0                        [256][16]
  __syncthreads();
  attn_layer<true>(bufA, bufB, as0, ad0, bb0, alpha, t); // h2 = relu(gat0 + bb0)
  __syncthreads();
  gemm_t<256, 256, false>(W1, nullptr, bufB, bufA, t);   // wh1
  __syncthreads();
  attn_layer<true>(bufA, bufB, as1, ad1, bb1, alpha, t); // h3 = relu(gat1 + bb1)
  __syncthreads();
  gemm_t<256, 256, false>(W2, nullptr, bufB, bufA, t);   // wh2
  __syncthreads();
  attn_layer<false>(bufA, bufB, as2, ad2, nullptr, alpha, t); // raw per-head agg
  __syncthreads();

  // head-mean + bb2 + node-mean pool:  g[c] = bb2[c] + (1/64) * sum_{h,n} agg[h*64+c][n]
  if (t < 64){
    float s = 0.f;
    #pragma unroll
    for (int hh = 0; hh < 4; ++hh)
      #pragma unroll
      for (int i = 0; i < 16; ++i)
        s += bufB[(hh*64 + t)*STRIDE + i];
    gsm[t] = bb2[t] + s * (1.f/64.f);
  }
  __syncthreads();

  // y = g @ w1 + b1  (128)
  float yv = 0.f;
  if (t < 128){
    yv = b1[t];
    #pragma unroll 4
    for (int k = 0; k < 64; ++k) yv += gsm[k] * w1[k*128 + t];
  }
  // LayerNorm over 128 features: two-wave reduction
  float s1 = (t < 128) ? yv      : 0.f;
  float s2 = (t < 128) ? yv * yv : 0.f;
  #pragma unroll
  for (int s = 1; s < 64; s <<= 1){ s1 += __shfl_xor(s1, s, 64); s2 += __shfl_xor(s2, s, 64); }
  if (t < 128 && (t & 63) == 0){ red[(t >> 6)*2] = s1; red[(t >> 6)*2 + 1] = s2; }
  __syncthreads();
  if (t < 128){
    const float mu  = (red[0] + red[2]) * (1.f/128.f);
    const float var = (red[1] + red[3]) * (1.f/128.f) - mu*mu;
    const float yn  = (yv - mu) * rsqrtf(var + 1e-5f) * lng[t] + lnb[t];
    ylds[t] = fmaxf(yn, 0.f);
  }
  __syncthreads();

  // out = relu(LN(y)) @ w2 + b2  (256)
  float acc = b2[t];
  #pragma unroll 4
  for (int k = 0; k < 128; ++k) acc += ylds[k] * w2[k*256 + t];
  out[b*256 + t] = acc;
}

extern "C" void kernel_launch(void* const* d_in, const int* in_sizes, int n_in,
                              void* d_out, int out_size, void* d_ws, size_t ws_size,
                              hipStream_t stream){
  const float* x    = (const float*)d_in[0];
  const float* w_in = (const float*)d_in[1];
  const float* b_in = (const float*)d_in[2];
  const float* W0   = (const float*)d_in[3];
  const float* as0  = (const float*)d_in[4];
  const float* ad0  = (const float*)d_in[5];
  const float* bb0  = (const float*)d_in[6];
  const float* W1   = (const float*)d_in[7];
  const float* as1  = (const float*)d_in[8];
  const float* ad1  = (const float*)d_in[9];
  const float* bb1  = (const float*)d_in[10];
  const float* W2   = (const float*)d_in[11];
  const float* as2  = (const float*)d_in[12];
  const float* ad2  = (const float*)d_in[13];
  const float* bb2  = (const float*)d_in[14];
  const float* w1   = (const float*)d_in[15];
  const float* b1   = (const float*)d_in[16];
  const float* lng  = (const float*)d_in[17];
  const float* lnb  = (const float*)d_in[18];
  const float* w2   = (const float*)d_in[19];
  const float* b2   = (const float*)d_in[20];
  const int B = in_sizes[0] / 256;

  gat_fused<<<B, 256, 0, stream>>>(x, w_in, b_in,
                                   W0, as0, ad0, bb0,
                                   W1, as1, ad1, bb1,
                                   W2, as2, ad2, bb2,
                                   w1, b1, lng, lnb, w2, b2,
                                   (float*)d_out);
}

// Round 2
// 393.421 us; speedup vs baseline: 4.2222x; 4.2222x over previous
//
#include <hip/hip_runtime.h>
#include <hip/hip_bf16.h>

typedef short s8v __attribute__((ext_vector_type(8)));
typedef float f4v __attribute__((ext_vector_type(4)));

#define HSTR 264   // bufH [32 nodes][264] bf16: stride*2/4 dw = 132 -> 4m%32 bank spread (2-way, free)
#define WSTR 36    // whT [272 feats][36] bf16: 18c%32 spread
#define ABS  40    // alphaT [8][16 i][40] bf16 (k 0..31 used)
#define H0S  40    // h0 [32][40] bf16 (k 0..31, cols 16..31 zeroed)

// 4x4 grid adjacency + self loops: bit j set => j is neighbor of i
__device__ constexpr unsigned KMASK[16] = {
  0x0013u,0x0027u,0x004Eu,0x008Cu,
  0x0131u,0x0272u,0x04E4u,0x08C8u,
  0x1310u,0x2720u,0x4E40u,0x8C80u,
  0x3100u,0x7200u,0xE400u,0xC800u};

__device__ __forceinline__ short f2b(float x){
  __hip_bfloat16 h = __float2bfloat16(x);
  return *reinterpret_cast<short*>(&h);
}
__device__ __forceinline__ float b2f(short s){
  __hip_bfloat16 h = *reinterpret_cast<__hip_bfloat16*>(&s);
  return __bfloat162float(h);
}

// ---------------- prep kernels: fp32 weights -> bf16 MFMA-B fragment order ----------------
// Layout: WP[((f*KS + s)*64 + lane)*8 + j] = W[k][n], n = f*16 + (lane&15), k = s*32 + (lane>>4)*8 + j
// ftile 16 holds score columns: n'=lane&15: 0..3 = WAsrc head n', 4..7 = WAdst head n'-4, 8..15 = 0.
template<int KS>
__global__ void prep_gat(const float* __restrict__ W, const float* __restrict__ asrc,
                         const float* __restrict__ adst, short* __restrict__ WP){
  const int fs = blockIdx.x;            // (16+1)*KS blocks
  const int f = fs / KS, s = fs % KS;
  const int l = threadIdx.x;            // 64
  const int lq = l & 15, quad = l >> 4;
  short v[8];
  if (f < 16){
    const int n = f*16 + lq;
    #pragma unroll
    for (int j = 0; j < 8; ++j){
      const int k = s*32 + quad*8 + j;
      v[j] = f2b(W[k*256 + n]);
    }
  } else {
    #pragma unroll
    for (int j = 0; j < 8; ++j){
      const int k = s*32 + quad*8 + j;
      float acc = 0.f;
      if (lq < 8){
        const float* a = (lq < 4) ? (asrc + lq*64) : (adst + (lq-4)*64);
        const float* wr = W + k*256 + (lq & 3)*64;
        for (int c = 0; c < 64; ++c) acc += wr[c] * a[c];
      }
      v[j] = f2b(acc);
    }
  }
  short* dst = WP + ((size_t)(f*KS + s)*64 + l)*8;
  #pragma unroll
  for (int j = 0; j < 8; ++j) dst[j] = v[j];
}

// w_in pack (OrientN A-operand): WPin[(mt*64+l)*8+j] = w_in[k][n], n = mt*16+(l&15), k = (l>>4)*8+j (0 for k>=16)
__global__ void prep_in(const float* __restrict__ w_in, short* __restrict__ WPin){
  const int f = blockIdx.x;             // 4
  const int l = threadIdx.x;            // 64
  const int lq = l & 15, quad = l >> 4;
  const int n = f*16 + lq;
  #pragma unroll
  for (int j = 0; j < 8; ++j){
    const int k = quad*8 + j;
    WPin[((size_t)(f*64 + l))*8 + j] = (k < 16) ? f2b(w_in[k*64 + n]) : (short)0;
  }
}

// ---------------- main fused kernel: 2 graphs per block, 256 threads ----------------
template<int KS, bool MEAN>
__device__ __forceinline__ void gat_layer(short* bufH, short* whT, short* alphaT,
    const short* __restrict__ WP, const float* __restrict__ bbias,
    float* gsm, const int t){
  const int l = t & 63, wv = t >> 6, lq = l & 15, quad = l >> 4;
  // ---- GEMM: whT[feat][node] = (H @ Wpack)^T, scores in rows 256..263 ----
  {
    f4v acc[5][2];
    #pragma unroll
    for (int fi = 0; fi < 5; ++fi)
      #pragma unroll
      for (int nt = 0; nt < 2; ++nt)
        acc[fi][nt] = (f4v){0.f,0.f,0.f,0.f};
    #pragma unroll 2
    for (int s = 0; s < KS; ++s){
      const s8v a0 = *(const s8v*)&bufH[lq*HSTR + s*32 + quad*8];        // A[m=node][k]
      const s8v a1 = *(const s8v*)&bufH[(16+lq)*HSTR + s*32 + quad*8];
      #pragma unroll
      for (int fi = 0; fi < 5; ++fi){
        if (fi == 4 && wv != 0) break;               // only wave 0 owns the score tile
        const int f = (fi == 4) ? 16 : (fi*4 + wv);
        const s8v bF = *(const s8v*)&WP[((f*KS + s)*64 + l)*8];          // B[k][n=outfeat]
        acc[fi][0] = __builtin_amdgcn_mfma_f32_16x16x32_bf16(a0, bF, acc[fi][0], 0,0,0);
        acc[fi][1] = __builtin_amdgcn_mfma_f32_16x16x32_bf16(a1, bF, acc[fi][1], 0,0,0);
      }
    }
    #pragma unroll
    for (int fi = 0; fi < 5; ++fi){
      if (fi == 4 && wv != 0) break;
      const int f = (fi == 4) ? 16 : (fi*4 + wv);
      #pragma unroll
      for (int nt = 0; nt < 2; ++nt){
        short4 p;                                     // D: col=outfeat(lq), rows=4 nodes
        p.x = f2b(acc[fi][nt][0]); p.y = f2b(acc[fi][nt][1]);
        p.z = f2b(acc[fi][nt][2]); p.w = f2b(acc[fi][nt][3]);
        *(short4*)&whT[(f*16 + lq)*WSTR + nt*16 + quad*4] = p;
      }
    }
  }
  __syncthreads();
  // ---- softmax: thread (g,h,i), writes alpha^T row i: B[k=node j][n=i], off-graph k zeroed ----
  if (t < 128){
    const int g = t >> 6, h = (t >> 4) & 3, i = t & 15;
    const float ed = b2f(whT[(260 + h)*WSTR + g*16 + i]);
    const unsigned m = KMASK[i];
    float ev[16]; float mx = -1e30f;
    #pragma unroll
    for (int j = 0; j < 16; ++j){
      float e = ed + b2f(whT[(256 + h)*WSTR + g*16 + j]);
      e = (e > 0.f) ? e : 0.2f*e;
      ev[j] = e;
      if ((m >> j) & 1u) mx = fmaxf(mx, e);
    }
    float ssum = 0.f;
    #pragma unroll
    for (int j = 0; j < 16; ++j){
      const float a = ((m >> j) & 1u) ? __expf(ev[j] - mx) : 0.f;
      ev[j] = a; ssum += a;
    }
    const float inv = 1.f / ssum;
    short* row = &alphaT[((h*2 + g)*16 + i)*ABS];
    const short4 z = make_short4(0,0,0,0);
    short4 vs[4];
    #pragma unroll
    for (int c4 = 0; c4 < 4; ++c4){
      vs[c4].x = f2b(ev[c4*4+0]*inv); vs[c4].y = f2b(ev[c4*4+1]*inv);
      vs[c4].z = f2b(ev[c4*4+2]*inv); vs[c4].w = f2b(ev[c4*4+3]*inv);
    }
    #pragma unroll
    for (int c4 = 0; c4 < 4; ++c4){
      ((short4*)row)[c4]     = g ? z : vs[c4];
      ((short4*)row)[4 + c4] = g ? vs[c4] : z;
    }
  }
  __syncthreads();
  // ---- aggregation: D = whT_tile x alpha^T  (D: col=node i, rows=4 consecutive feats) ----
  if constexpr (!MEAN){
    const int h = wv;                                 // wave == head
    #pragma unroll
    for (int ct = 0; ct < 4; ++ct){
      const s8v a = *(const s8v*)&whT[(h*64 + ct*16 + lq)*WSTR + quad*8];
      #pragma unroll
      for (int g = 0; g < 2; ++g){
        const s8v bA = *(const s8v*)&alphaT[((h*2 + g)*16 + lq)*ABS + quad*8];
        f4v d = (f4v){0.f,0.f,0.f,0.f};
        d = __builtin_amdgcn_mfma_f32_16x16x32_bf16(a, bA, d, 0,0,0);
        const int f0 = h*64 + ct*16 + quad*4;
        const float4 bb = *(const float4*)&bbias[f0];
        short4 p;
        p.x = f2b(fmaxf(d[0] + bb.x, 0.f)); p.y = f2b(fmaxf(d[1] + bb.y, 0.f));
        p.z = f2b(fmaxf(d[2] + bb.z, 0.f)); p.w = f2b(fmaxf(d[3] + bb.w, 0.f));
        *(short4*)&bufH[(g*16 + lq)*HSTR + f0] = p;
      }
    }
  } else {
    // mean over heads + node-mean pool, straight into gsm[g][64]
    const int g = wv >> 1;
    #pragma unroll
    for (int cc = 0; cc < 2; ++cc){
      const int ct = (wv & 1)*2 + cc;
      f4v d = (f4v){0.f,0.f,0.f,0.f};
      #pragma unroll
      for (int h = 0; h < 4; ++h){
        const s8v a  = *(const s8v*)&whT[(h*64 + ct*16 + lq)*WSTR + quad*8];
        const s8v bA = *(const s8v*)&alphaT[((h*2 + g)*16 + lq)*ABS + quad*8];
        d = __builtin_amdgcn_mfma_f32_16x16x32_bf16(a, bA, d, 0,0,0);
      }
      #pragma unroll
      for (int s = 1; s < 16; s <<= 1){               // sum over node i (lanes lq)
        d[0] += __shfl_xor(d[0], s, 64); d[1] += __shfl_xor(d[1], s, 64);
        d[2] += __shfl_xor(d[2], s, 64); d[3] += __shfl_xor(d[3], s, 64);
      }
      if (lq == 0){
        const int f0 = ct*16 + quad*4;
        const float4 bb = *(const float4*)&bbias[f0];
        float4 gv;
        gv.x = d[0]*(1.f/64.f) + bb.x; gv.y = d[1]*(1.f/64.f) + bb.y;
        gv.z = d[2]*(1.f/64.f) + bb.z; gv.w = d[3]*(1.f/64.f) + bb.w;
        *(float4*)&gsm[g*64 + f0] = gv;
      }
    }
  }
}

__global__ __launch_bounds__(256, 3) void gat_main(
  const float* __restrict__ x,
  const short* __restrict__ WPin, const float* __restrict__ b_in,
  const short* __restrict__ WP0,  const float* __restrict__ bb0,
  const short* __restrict__ WP1,  const float* __restrict__ bb1,
  const short* __restrict__ WP2,  const float* __restrict__ bb2,
  const float* __restrict__ w1,   const float* __restrict__ b1,
  const float* __restrict__ lng,  const float* __restrict__ lnb,
  const float* __restrict__ w2,   const float* __restrict__ b2,
  float* __restrict__ out)
{
  __shared__ short bufH[32*HSTR];     // 16,896 B
  __shared__ short whT[272*WSTR];     // 19,584 B
  __shared__ short alphaT[8*16*ABS];  // 10,240 B
  __shared__ short h0[32*H0S];        //  2,560 B
  __shared__ float gsm[128];
  __shared__ float ylds[256];
  __shared__ float red[8];

  const int b = blockIdx.x;
  const int t = threadIdx.x;
  const int l = t & 63, wv = t >> 6, lq = l & 15, quad = l >> 4;

  // stage x: h0[node][ch] = x[b2, ch, node], zero-pad k 16..31
  {
    const float2 v = *(const float2*)&x[b*512 + 2*t];
    const int i0 = 2*t;
    const int g = i0 >> 8, c = (i0 >> 4) & 15, n = i0 & 15;
    h0[(g*16 + n)*H0S + c]     = f2b(v.x);
    h0[(g*16 + n + 1)*H0S + c] = f2b(v.y);
    const int r = t >> 3, cc = 16 + 2*(t & 7);
    h0[r*H0S + cc] = 0; h0[r*H0S + cc + 1] = 0;
  }
  __syncthreads();

  // h1 = relu(h0 @ w_in + b_in): A = w_in^T pack, B = h0 rows, D: col=node, rows=4 feats
  {
    const s8v aF = *(const s8v*)&WPin[(wv*64 + l)*8];
    const s8v b0 = *(const s8v*)&h0[lq*H0S + quad*8];
    const s8v b1v = *(const s8v*)&h0[(16+lq)*H0S + quad*8];
    f4v acc0 = (f4v){0.f,0.f,0.f,0.f}, acc1 = (f4v){0.f,0.f,0.f,0.f};
    acc0 = __builtin_amdgcn_mfma_f32_16x16x32_bf16(aF, b0,  acc0, 0,0,0);
    acc1 = __builtin_amdgcn_mfma_f32_16x16x32_bf16(aF, b1v, acc1, 0,0,0);
    const int f0 = wv*16 + quad*4;
    const float4 bi = *(const float4*)&b_in[f0];
    short4 p0, p1;
    p0.x = f2b(fmaxf(acc0[0]+bi.x,0.f)); p0.y = f2b(fmaxf(acc0[1]+bi.y,0.f));
    p0.z = f2b(fmaxf(acc0[2]+bi.z,0.f)); p0.w = f2b(fmaxf(acc0[3]+bi.w,0.f));
    p1.x = f2b(fmaxf(acc1[0]+bi.x,0.f)); p1.y = f2b(fmaxf(acc1[1]+bi.y,0.f));
    p1.z = f2b(fmaxf(acc1[2]+bi.z,0.f)); p1.w = f2b(fmaxf(acc1[3]+bi.w,0.f));
    *(short4*)&bufH[lq*HSTR + f0]      = p0;
    *(short4*)&bufH[(16+lq)*HSTR + f0] = p1;
  }
  __syncthreads();

  gat_layer<2, false>(bufH, whT, alphaT, WP0, bb0, gsm, t);
  __syncthreads();
  gat_layer<8, false>(bufH, whT, alphaT, WP1, bb1, gsm, t);
  __syncthreads();
  gat_layer<8, true >(bufH, whT, alphaT, WP2, bb2, gsm, t);
  __syncthreads();

  // ---- MLP tail (fp32): y = g@w1+b1, LN, relu, @w2+b2 ----
  const int gg = t >> 7, o = t & 127;
  float yv = b1[o];
  #pragma unroll 8
  for (int k = 0; k < 64; ++k) yv += gsm[gg*64 + k] * w1[k*128 + o];
  float s1 = yv, s2 = yv*yv;
  #pragma unroll
  for (int s = 1; s < 64; s <<= 1){ s1 += __shfl_xor(s1, s, 64); s2 += __shfl_xor(s2, s, 64); }
  if ((t & 63) == 0){ red[(t>>6)*2] = s1; red[(t>>6)*2+1] = s2; }
  __syncthreads();
  {
    const float S1 = red[4*gg] + red[4*gg+2], S2 = red[4*gg+1] + red[4*gg+3];
    const float mu  = S1 * (1.f/128.f);
    const float var = S2 * (1.f/128.f) - mu*mu;
    const float yn  = (yv - mu) * rsqrtf(var + 1e-5f) * lng[o] + lnb[o];
    ylds[gg*128 + o] = fmaxf(yn, 0.f);
  }
  __syncthreads();
  float a0 = b2[t], a1 = b2[t];
  #pragma unroll 4
  for (int k = 0; k < 128; ++k){
    const float wv2 = w2[k*256 + t];
    a0 += ylds[k]*wv2; a1 += ylds[128+k]*wv2;
  }
  out[(b*2+0)*256 + t] = a0;
  out[(b*2+1)*256 + t] = a1;
}

extern "C" void kernel_launch(void* const* d_in, const int* in_sizes, int n_in,
                              void* d_out, int out_size, void* d_ws, size_t ws_size,
                              hipStream_t stream){
  const float* x    = (const float*)d_in[0];
  const float* w_in = (const float*)d_in[1];
  const float* b_in = (const float*)d_in[2];
  const float* W0   = (const float*)d_in[3];
  const float* as0  = (const float*)d_in[4];
  const float* ad0  = (const float*)d_in[5];
  const float* bb0  = (const float*)d_in[6];
  const float* W1   = (const float*)d_in[7];
  const float* as1  = (const float*)d_in[8];
  const float* ad1  = (const float*)d_in[9];
  const float* bb1  = (const float*)d_in[10];
  const float* W2   = (const float*)d_in[11];
  const float* as2  = (const float*)d_in[12];
  const float* ad2  = (const float*)d_in[13];
  const float* bb2  = (const float*)d_in[14];
  const float* w1   = (const float*)d_in[15];
  const float* b1   = (const float*)d_in[16];
  const float* lng  = (const float*)d_in[17];
  const float* lnb  = (const float*)d_in[18];
  const float* w2   = (const float*)d_in[19];
  const float* b2   = (const float*)d_in[20];
  const int B = in_sizes[0] / 256;

  short* ws   = (short*)d_ws;
  short* WPin = ws;                    //  4*64*8      =  2,048 shorts
  short* WP0  = ws + 2048;             // 17*2*64*8    = 17,408
  short* WP1  = ws + 19456;            // 17*8*64*8    = 69,632
  short* WP2  = ws + 89088;            // 69,632  (end 158,720 shorts = 310 KB)

  prep_in <<<4,   64, 0, stream>>>(w_in, WPin);
  prep_gat<2><<<34,  64, 0, stream>>>(W0, as0, ad0, WP0);
  prep_gat<8><<<136, 64, 0, stream>>>(W1, as1, ad1, WP1);
  prep_gat<8><<<136, 64, 0, stream>>>(W2, as2, ad2, WP2);

  gat_main<<<B/2, 256, 0, stream>>>(x, WPin, b_in, WP0, bb0, WP1, bb1, WP2, bb2,
                                    w1, b1, lng, lnb, w2, b2, (float*)d_out);
}

// Round 5
// 335.967 us; speedup vs baseline: 4.9442x; 1.1710x over previous
//
#include <hip/hip_runtime.h>
#include <hip/hip_bf16.h>

typedef short s8v __attribute__((ext_vector_type(8)));
typedef short s4v __attribute__((ext_vector_type(4)));
typedef float f4v __attribute__((ext_vector_type(4)));

#define HSTR 264   // bufH [32 nodes][264] bf16 rows: 528B, 16B-aligned
#define WSTR 36    // whT  [264 feats][36] bf16 rows
#define AP   18    // alphaS [8 (g*4+h)][16 i][18] bf16 (16 used)

// 4x4 grid adjacency + self loops: bit j set => j is neighbor of i
__device__ constexpr unsigned KMASK[16] = {
  0x0013u,0x0027u,0x004Eu,0x008Cu,
  0x0131u,0x0272u,0x04E4u,0x08C8u,
  0x1310u,0x2720u,0x4E40u,0x8C80u,
  0x3100u,0x7200u,0xE400u,0xC800u};

__device__ __forceinline__ short f2b(float x){
  __hip_bfloat16 h = __float2bfloat16(x);
  return *reinterpret_cast<short*>(&h);
}
__device__ __forceinline__ float b2f(short s){
  __hip_bfloat16 h = *reinterpret_cast<__hip_bfloat16*>(&s);
  return __bfloat162float(h);
}

// ======================= single prep kernel =======================
// WP layout: WP[((f*KS + s)*64 + lane)*8 + j] = W[k][n], n=f*16+(lane&15), k=s*32+(lane>>4)*8+j
// ftile 16 = score columns: col 0..3 = sum_c W[k][col*64+c]*asrc[col][c]; 4..7 same w/ adst; 8..15 zero
// Total ws use: 158,720 shorts = 317,440 B (same footprint as the validated round-2 layout).
__global__ __launch_bounds__(256) void prep_all(
  const float* __restrict__ W0, const float* __restrict__ as0, const float* __restrict__ ad0,
  const float* __restrict__ W1, const float* __restrict__ as1, const float* __restrict__ ad1,
  const float* __restrict__ W2, const float* __restrict__ as2, const float* __restrict__ ad2,
  const float* __restrict__ w_in,
  short* __restrict__ ws)
{
  short* WPin = ws;
  short* WP0  = ws + 2048;
  short* WP1  = ws + 2048 + 17408;
  short* WP2  = ws + 2048 + 17408 + 69632;

  const int t = threadIdx.x, l = t & 63;
  const int gid = blockIdx.x*4 + (t >> 6);

  if (gid < 288){                       // ---- main weight pack ----
    const float* W; short* WP; int u = gid, f, s, KS;
    if (u < 32)      { W = W0; WP = WP0; KS = 2; f = u >> 1; s = u & 1; }
    else if (u < 160){ u -= 32;  W = W1; WP = WP1; KS = 8; f = u >> 3; s = u & 7; }
    else             { u -= 160; W = W2; WP = WP2; KS = 8; f = u >> 3; s = u & 7; }
    const int lq = l & 15, quad = l >> 4;
    union { s8v v; short s16[8]; } o;
    #pragma unroll
    for (int j = 0; j < 8; ++j)
      o.s16[j] = f2b(W[(s*32 + quad*8 + j)*256 + f*16 + lq]);
    *(s8v*)(WP + ((f*KS + s)*64 + l)*8) = o.v;
  } else if (gid < 292){                // ---- w_in pack (A-operand layout) ----
    const int f = gid - 288;
    const int lq = l & 15, quad = l >> 4;
    union { s8v v; short s16[8]; } o;
    #pragma unroll
    for (int j = 0; j < 8; ++j){
      const int k = quad*8 + j;
      o.s16[j] = (k < 16) ? f2b(w_in[k*64 + f*16 + lq]) : (short)0;
    }
    *(s8v*)(WPin + (f*64 + l)*8) = o.v;
  } else {                              // ---- score columns, one wave per k-row (gid 292..867) ----
    int u = gid - 292;
    const float* W; const float* as; const float* ad; short* WP; int KS, k;
    if (u < 64)      { W=W0; as=as0; ad=ad0; WP=WP0; KS=2; k=u; }
    else if (u < 320){ u-=64;  W=W1; as=as1; ad=ad1; WP=WP1; KS=8; k=u; }
    else             { u-=320; W=W2; as=as2; ad=ad2; WP=WP2; KS=8; k=u; }
    float v[8];
    #pragma unroll
    for (int h = 0; h < 4; ++h){
      const float wv_ = W[k*256 + h*64 + l];
      v[h]   = wv_ * as[h*64 + l];
      v[4+h] = wv_ * ad[h*64 + l];
    }
    #pragma unroll
    for (int s = 1; s < 64; s <<= 1)
      #pragma unroll
      for (int uu = 0; uu < 8; ++uu) v[uu] += __shfl_xor(v[uu], s, 64);
    if (l < 16){
      const float r = (l < 8) ? v[l] : 0.f;
      WP[((16*KS + (k >> 5))*64 + ((k >> 3) & 3)*16 + l)*8 + (k & 7)] = f2b(r);
    }
  }
}

// ======================= main fused kernel =======================
template<int KS, bool MEAN>
__device__ __forceinline__ void gat_layer(short* bufH, short* whT, short* alphaS,
    const short* __restrict__ WP, const float* __restrict__ bbias,
    float* gsm, const int t)
{
  const int l = t & 63, wv = t >> 6, lq = l & 15, quad = l >> 4;
  // ---- GEMM: whT[feat][node] (+ score rows 256..263); wave 3 owns the score tile ----
  {
    f4v acc[5][2];
    #pragma unroll
    for (int fi = 0; fi < 5; ++fi)
      #pragma unroll
      for (int nt = 0; nt < 2; ++nt) acc[fi][nt] = (f4v){0.f,0.f,0.f,0.f};
    #pragma unroll 2
    for (int s = 0; s < KS; ++s){
      const s8v a0 = *(const s8v*)&bufH[lq*HSTR + s*32 + quad*8];
      const s8v a1 = *(const s8v*)&bufH[(16+lq)*HSTR + s*32 + quad*8];
      #pragma unroll
      for (int fi = 0; fi < 5; ++fi){
        if (fi == 4 && wv != 3) break;
        const int f = (fi == 4) ? 16 : fi*4 + wv;
        const s8v bF = *(const s8v*)&WP[((f*KS + s)*64 + l)*8];
        acc[fi][0] = __builtin_amdgcn_mfma_f32_16x16x32_bf16(a0, bF, acc[fi][0], 0,0,0);
        acc[fi][1] = __builtin_amdgcn_mfma_f32_16x16x32_bf16(a1, bF, acc[fi][1], 0,0,0);
      }
    }
    #pragma unroll
    for (int fi = 0; fi < 5; ++fi){
      if (fi == 4 && (wv != 3 || lq >= 8)) break;  // score cols 8..15 are structural zeros (rows 264+ OOB)
      const int f = (fi == 4) ? 16 : fi*4 + wv;
      #pragma unroll
      for (int nt = 0; nt < 2; ++nt){
        short4 p;
        p.x = f2b(acc[fi][nt][0]); p.y = f2b(acc[fi][nt][1]);
        p.z = f2b(acc[fi][nt][2]); p.w = f2b(acc[fi][nt][3]);
        *(short4*)&whT[(f*16 + lq)*WSTR + nt*16 + quad*4] = p;
      }
    }
  }
  __syncthreads();
  // ---- softmax: thread (g,h,i) -> alphaS row (g*4+h, i), 16 bf16 ----
  if (t < 128){
    const int g = t >> 6, h = (t >> 4) & 3, i = t & 15;
    const float ed = b2f(whT[(260 + h)*WSTR + g*16 + i]);
    float ev[16];
    #pragma unroll
    for (int c = 0; c < 4; ++c){
      const s4v v = *(const s4v*)&whT[(256 + h)*WSTR + g*16 + c*4];
      ev[c*4+0]=b2f(v[0]); ev[c*4+1]=b2f(v[1]); ev[c*4+2]=b2f(v[2]); ev[c*4+3]=b2f(v[3]);
    }
    const unsigned m = KMASK[i];
    float mx = -1e30f;
    #pragma unroll
    for (int j = 0; j < 16; ++j){
      float e = ed + ev[j];
      e = (e > 0.f) ? e : 0.2f*e;
      ev[j] = e;
      if ((m >> j) & 1u) mx = fmaxf(mx, e);
    }
    float ssum = 0.f;
    #pragma unroll
    for (int j = 0; j < 16; ++j){
      const float a = ((m >> j) & 1u) ? __expf(ev[j] - mx) : 0.f;
      ev[j] = a; ssum += a;
    }
    const float inv = 1.f / ssum;
    unsigned* row = (unsigned*)&alphaS[((g*4 + h)*16 + i)*AP];
    #pragma unroll
    for (int c = 0; c < 8; ++c){
      const unsigned lo = (unsigned)(unsigned short)f2b(ev[2*c]*inv);
      const unsigned hi = (unsigned)(unsigned short)f2b(ev[2*c+1]*inv);
      row[c] = lo | (hi << 16);
    }
  }
  __syncthreads();
  // ---- aggregation: B-operand built in regs (zero half selected by quad vs g) ----
  if constexpr (!MEAN){
    const int h = wv;
    union { s8v v; unsigned u[4]; } B[2];
    #pragma unroll
    for (int g = 0; g < 2; ++g){
      const unsigned* ar = (const unsigned*)&alphaS[((g*4 + h)*16 + lq)*AP + (quad & 1)*8];
      const bool act = ((quad >> 1) == g);
      #pragma unroll
      for (int c = 0; c < 4; ++c) B[g].u[c] = act ? ar[c] : 0u;
    }
    #pragma unroll
    for (int ct = 0; ct < 4; ++ct){
      const s8v a = *(const s8v*)&whT[(h*64 + ct*16 + lq)*WSTR + quad*8];
      #pragma unroll
      for (int g = 0; g < 2; ++g){
        f4v d = (f4v){0.f,0.f,0.f,0.f};
        d = __builtin_amdgcn_mfma_f32_16x16x32_bf16(a, B[g].v, d, 0,0,0);
        const int f0 = h*64 + ct*16 + quad*4;
        const float4 bb = *(const float4*)&bbias[f0];
        short4 p;
        p.x = f2b(fmaxf(d[0] + bb.x, 0.f)); p.y = f2b(fmaxf(d[1] + bb.y, 0.f));
        p.z = f2b(fmaxf(d[2] + bb.z, 0.f)); p.w = f2b(fmaxf(d[3] + bb.w, 0.f));
        *(short4*)&bufH[(g*16 + lq)*HSTR + f0] = p;
      }
    }
  } else {
    const int g = wv >> 1;
    union { s8v v; unsigned u[4]; } B[4];
    #pragma unroll
    for (int h = 0; h < 4; ++h){
      const unsigned* ar = (const unsigned*)&alphaS[((g*4 + h)*16 + lq)*AP + (quad & 1)*8];
      const bool act = ((quad >> 1) == g);
      #pragma unroll
      for (int c = 0; c < 4; ++c) B[h].u[c] = act ? ar[c] : 0u;
    }
    #pragma unroll
    for (int cc = 0; cc < 2; ++cc){
      const int ct = (wv & 1)*2 + cc;
      f4v d = (f4v){0.f,0.f,0.f,0.f};
      #pragma unroll
      for (int h = 0; h < 4; ++h){
        const s8v a = *(const s8v*)&whT[(h*64 + ct*16 + lq)*WSTR + quad*8];
        d = __builtin_amdgcn_mfma_f32_16x16x32_bf16(a, B[h].v, d, 0,0,0);
      }
      #pragma unroll
      for (int s = 1; s < 16; s <<= 1){
        d[0] += __shfl_xor(d[0], s, 64); d[1] += __shfl_xor(d[1], s, 64);
        d[2] += __shfl_xor(d[2], s, 64); d[3] += __shfl_xor(d[3], s, 64);
      }
      if (lq == 0){
        const int f0 = ct*16 + quad*4;
        const float4 bb = *(const float4*)&bbias[f0];
        float4 gv;
        gv.x = d[0]*(1.f/64.f) + bb.x; gv.y = d[1]*(1.f/64.f) + bb.y;
        gv.z = d[2]*(1.f/64.f) + bb.z; gv.w = d[3]*(1.f/64.f) + bb.w;
        *(float4*)&gsm[g*64 + f0] = gv;
      }
    }
  }
}

__global__ __launch_bounds__(256, 4) void gat_main(
  const float* __restrict__ x,
  const short* __restrict__ WPin, const float* __restrict__ b_in,
  const short* __restrict__ WP0,  const float* __restrict__ bb0,
  const short* __restrict__ WP1,  const float* __restrict__ bb1,
  const short* __restrict__ WP2,  const float* __restrict__ bb2,
  const float* __restrict__ w1,   const float* __restrict__ b1,
  const float* __restrict__ lng,  const float* __restrict__ lnb,
  const float* __restrict__ w2,   const float* __restrict__ b2,
  float* __restrict__ out)
{
  // Single LDS block, explicit deterministic carve. 20,256 shorts = 40,512 B -> 4 blocks/CU (162,048 <= 163,840).
  __shared__ __align__(16) short smem[32*HSTR + 264*WSTR + 8*16*AP];
  short* bufH   = smem;                        // [32][HSTR]      8,448 shorts
  short* whT    = smem + 32*HSTR;              // [264][WSTR]     9,504 shorts
  short* alphaS = smem + 32*HSTR + 264*WSTR;   // [8][16][AP]     2,304 shorts
  short* h0   = whT;                           // [32][40] staging alias (dead before whT is written)
  float* gsm  = (float*)bufH;                  // [128] tail alias (bufH dead after last GEMM)
  float* ylds = gsm + 128;                     // [256]
  float* red  = ylds + 256;                    // [8]
  constexpr int H0S = 40;

  const int b = blockIdx.x;
  const int t = threadIdx.x;
  const int l = t & 63, wv = t >> 6, lq = l & 15, quad = l >> 4;

  // stage x: h0[node][ch], zero-pad ch 16..31
  {
    const float2 v = *(const float2*)&x[b*512 + 2*t];
    const int i0 = 2*t;
    const int g = i0 >> 8, c = (i0 >> 4) & 15, n = i0 & 15;
    h0[(g*16 + n)*H0S + c]     = f2b(v.x);
    h0[(g*16 + n + 1)*H0S + c] = f2b(v.y);
    const int r = t >> 3, cc = 16 + 2*(t & 7);
    h0[r*H0S + cc] = 0; h0[r*H0S + cc + 1] = 0;
  }
  __syncthreads();

  // h1 = relu(h0 @ w_in + b_in) -> bufH[node][feat<64]
  {
    const s8v aF  = *(const s8v*)&WPin[(wv*64 + l)*8];
    const s8v b0v = *(const s8v*)&h0[lq*H0S + quad*8];
    const s8v b1v = *(const s8v*)&h0[(16+lq)*H0S + quad*8];
    f4v acc0 = (f4v){0.f,0.f,0.f,0.f}, acc1 = (f4v){0.f,0.f,0.f,0.f};
    acc0 = __builtin_amdgcn_mfma_f32_16x16x32_bf16(aF, b0v, acc0, 0,0,0);
    acc1 = __builtin_amdgcn_mfma_f32_16x16x32_bf16(aF, b1v, acc1, 0,0,0);
    const int f0 = wv*16 + quad*4;
    const float4 bi = *(const float4*)&b_in[f0];
    short4 p0, p1;
    p0.x = f2b(fmaxf(acc0[0]+bi.x,0.f)); p0.y = f2b(fmaxf(acc0[1]+bi.y,0.f));
    p0.z = f2b(fmaxf(acc0[2]+bi.z,0.f)); p0.w = f2b(fmaxf(acc0[3]+bi.w,0.f));
    p1.x = f2b(fmaxf(acc1[0]+bi.x,0.f)); p1.y = f2b(fmaxf(acc1[1]+bi.y,0.f));
    p1.z = f2b(fmaxf(acc1[2]+bi.z,0.f)); p1.w = f2b(fmaxf(acc1[3]+bi.w,0.f));
    *(short4*)&bufH[lq*HSTR + f0]      = p0;
    *(short4*)&bufH[(16+lq)*HSTR + f0] = p1;
  }
  __syncthreads();

  gat_layer<2, false>(bufH, whT, alphaS, WP0, bb0, gsm, t);
  __syncthreads();
  gat_layer<8, false>(bufH, whT, alphaS, WP1, bb1, gsm, t);
  __syncthreads();
  gat_layer<8, true >(bufH, whT, alphaS, WP2, bb2, gsm, t);
  __syncthreads();

  // ---- MLP tail (fp32 weights, round-2-proven): y = g@w1+b1, LN, relu, @w2+b2 ----
  const int gg = t >> 7, o = t & 127;
  float yv = b1[o];
  #pragma unroll 8
  for (int k = 0; k < 64; ++k) yv += gsm[gg*64 + k] * w1[k*128 + o];
  float s1 = yv, s2 = yv*yv;
  #pragma unroll
  for (int s = 1; s < 64; s <<= 1){ s1 += __shfl_xor(s1, s, 64); s2 += __shfl_xor(s2, s, 64); }
  if ((t & 63) == 0){ red[(t>>6)*2] = s1; red[(t>>6)*2 + 1] = s2; }
  __syncthreads();
  {
    const float S1 = red[4*gg] + red[4*gg+2], S2 = red[4*gg+1] + red[4*gg+3];
    const float mu  = S1 * (1.f/128.f);
    const float var = S2 * (1.f/128.f) - mu*mu;
    const float yn  = (yv - mu) * rsqrtf(var + 1e-5f) * lng[o] + lnb[o];
    ylds[gg*128 + o] = fmaxf(yn, 0.f);
  }
  __syncthreads();
  float a0 = b2[t], a1 = b2[t];
  #pragma unroll 4
  for (int k = 0; k < 128; ++k){
    const float wv2 = w2[k*256 + t];
    a0 += ylds[k]*wv2; a1 += ylds[128 + k]*wv2;
  }
  out[(b*2 + 0)*256 + t] = a0;
  out[(b*2 + 1)*256 + t] = a1;
}

extern "C" void kernel_launch(void* const* d_in, const int* in_sizes, int n_in,
                              void* d_out, int out_size, void* d_ws, size_t ws_size,
                              hipStream_t stream){
  const float* x    = (const float*)d_in[0];
  const float* w_in = (const float*)d_in[1];
  const float* b_in = (const float*)d_in[2];
  const float* W0   = (const float*)d_in[3];
  const float* as0  = (const float*)d_in[4];
  const float* ad0  = (const float*)d_in[5];
  const float* bb0  = (const float*)d_in[6];
  const float* W1   = (const float*)d_in[7];
  const float* as1  = (const float*)d_in[8];
  const float* ad1  = (const float*)d_in[9];
  const float* bb1  = (const float*)d_in[10];
  const float* W2   = (const float*)d_in[11];
  const float* as2  = (const float*)d_in[12];
  const float* ad2  = (const float*)d_in[13];
  const float* bb2  = (const float*)d_in[14];
  const float* w1   = (const float*)d_in[15];
  const float* b1   = (const float*)d_in[16];
  const float* lng  = (const float*)d_in[17];
  const float* lnb  = (const float*)d_in[18];
  const float* w2   = (const float*)d_in[19];
  const float* b2   = (const float*)d_in[20];
  const int B = in_sizes[0] / 256;

  short* ws = (short*)d_ws;
  const short* WPin = ws;
  const short* WP0  = ws + 2048;
  const short* WP1  = ws + 2048 + 17408;
  const short* WP2  = ws + 2048 + 17408 + 69632;   // ends at 158,720 shorts = 317,440 B (validated footprint)

  prep_all<<<217, 256, 0, stream>>>(W0, as0, ad0, W1, as1, ad1, W2, as2, ad2,
                                    w_in, ws);
  gat_main<<<B/2, 256, 0, stream>>>(x, WPin, b_in, WP0, bb0, WP1, bb1, WP2, bb2,
                                    w1, b1, lng, lnb, w2, b2, (float*)d_out);
}

// Round 6
// 330.184 us; speedup vs baseline: 5.0308x; 1.0175x over previous
//
#include <hip/hip_runtime.h>
#include <hip/hip_bf16.h>

typedef short s8v __attribute__((ext_vector_type(8)));
typedef short s4v __attribute__((ext_vector_type(4)));
typedef float f4v __attribute__((ext_vector_type(4)));

#define WSTR 36    // whT  [264 feats][36] bf16 rows
#define AP   20    // alphaS [8 (g*4+h)][16 i][20] bf16 (16 used); 10dw row stride -> 16 distinct banks

// bufH: MFMA-A fragment-major: element (feat f, node n) at (( (f>>5)*4 + ((f>>3)&3) )*32 + n)*8 + (f&7)
// => a wave's A-read (16 lanes x 16B, consecutive nodes) is contiguous -> conflict-free.
#define HIXBASE(s, quad) (((s)*4 + (quad))*256)

// 4x4 grid adjacency + self loops: bit j set => j is neighbor of i
__device__ constexpr unsigned KMASK[16] = {
  0x0013u,0x0027u,0x004Eu,0x008Cu,
  0x0131u,0x0272u,0x04E4u,0x08C8u,
  0x1310u,0x2720u,0x4E40u,0x8C80u,
  0x3100u,0x7200u,0xE400u,0xC800u};

__device__ __forceinline__ short f2b(float x){            // prep-kernel only (cold)
  __hip_bfloat16 h = __float2bfloat16(x);
  return *reinterpret_cast<short*>(&h);
}
__device__ __forceinline__ float b2f(short s){
  __hip_bfloat16 h = *reinterpret_cast<__hip_bfloat16*>(&s);
  return __bfloat162float(h);
}
// fast RNE bf16 pair pack: low16=a, hi16=b. Inputs finite (no NaN guard needed).
__device__ __forceinline__ unsigned pk2(float a, float b){
  unsigned ua = __float_as_uint(a), ub = __float_as_uint(b);
  ua += 0x7fffu + ((ua >> 16) & 1u);
  ub += 0x7fffu + ((ub >> 16) & 1u);
  return __builtin_amdgcn_perm(ub, ua, 0x07060302);       // bytes: ua.b2,ua.b3,ub.b2,ub.b3
}

// ======================= single prep kernel (unchanged, validated) =======================
// WP layout: WP[((f*KS + s)*64 + lane)*8 + j] = W[k][n], n=f*16+(lane&15), k=s*32+(lane>>4)*8+j
// ftile 16 = score columns: col 0..3 = sum_c W[k][col*64+c]*asrc[col][c]; 4..7 same w/ adst; 8..15 zero
__global__ __launch_bounds__(256) void prep_all(
  const float* __restrict__ W0, const float* __restrict__ as0, const float* __restrict__ ad0,
  const float* __restrict__ W1, const float* __restrict__ as1, const float* __restrict__ ad1,
  const float* __restrict__ W2, const float* __restrict__ as2, const float* __restrict__ ad2,
  const float* __restrict__ w_in,
  short* __restrict__ ws)
{
  short* WPin = ws;
  short* WP0  = ws + 2048;
  short* WP1  = ws + 2048 + 17408;
  short* WP2  = ws + 2048 + 17408 + 69632;

  const int t = threadIdx.x, l = t & 63;
  const int gid = blockIdx.x*4 + (t >> 6);

  if (gid < 288){                       // ---- main weight pack ----
    const float* W; short* WP; int u = gid, f, s, KS;
    if (u < 32)      { W = W0; WP = WP0; KS = 2; f = u >> 1; s = u & 1; }
    else if (u < 160){ u -= 32;  W = W1; WP = WP1; KS = 8; f = u >> 3; s = u & 7; }
    else             { u -= 160; W = W2; WP = WP2; KS = 8; f = u >> 3; s = u & 7; }
    const int lq = l & 15, quad = l >> 4;
    union { s8v v; short s16[8]; } o;
    #pragma unroll
    for (int j = 0; j < 8; ++j)
      o.s16[j] = f2b(W[(s*32 + quad*8 + j)*256 + f*16 + lq]);
    *(s8v*)(WP + ((f*KS + s)*64 + l)*8) = o.v;
  } else if (gid < 292){                // ---- w_in pack (A-operand layout) ----
    const int f = gid - 288;
    const int lq = l & 15, quad = l >> 4;
    union { s8v v; short s16[8]; } o;
    #pragma unroll
    for (int j = 0; j < 8; ++j){
      const int k = quad*8 + j;
      o.s16[j] = (k < 16) ? f2b(w_in[k*64 + f*16 + lq]) : (short)0;
    }
    *(s8v*)(WPin + (f*64 + l)*8) = o.v;
  } else {                              // ---- score columns, one wave per k-row ----
    int u = gid - 292;
    const float* W; const float* as; const float* ad; short* WP; int KS, k;
    if (u < 64)      { W=W0; as=as0; ad=ad0; WP=WP0; KS=2; k=u; }
    else if (u < 320){ u-=64;  W=W1; as=as1; ad=ad1; WP=WP1; KS=8; k=u; }
    else             { u-=320; W=W2; as=as2; ad=ad2; WP=WP2; KS=8; k=u; }
    float v[8];
    #pragma unroll
    for (int h = 0; h < 4; ++h){
      const float wv_ = W[k*256 + h*64 + l];
      v[h]   = wv_ * as[h*64 + l];
      v[4+h] = wv_ * ad[h*64 + l];
    }
    #pragma unroll
    for (int s = 1; s < 64; s <<= 1)
      #pragma unroll
      for (int uu = 0; uu < 8; ++uu) v[uu] += __shfl_xor(v[uu], s, 64);
    if (l < 16){
      const float r = (l < 8) ? v[l] : 0.f;
      WP[((16*KS + (k >> 5))*64 + ((k >> 3) & 3)*16 + l)*8 + (k & 7)] = f2b(r);
    }
  }
}

// ======================= main fused kernel =======================
template<int KS, bool MEAN>
__device__ __forceinline__ void gat_layer(short* bufH, short* whT, short* alphaS,
    const short* __restrict__ WP, const float* __restrict__ bbias,
    float* gsm, const int t)
{
  const int l = t & 63, wv = t >> 6, lq = l & 15, quad = l >> 4;
  // ---- GEMM: whT[feat][node] (+ score rows 256..263); wave 3 owns the score tile ----
  {
    f4v acc[5][2];
    #pragma unroll
    for (int fi = 0; fi < 5; ++fi)
      #pragma unroll
      for (int nt = 0; nt < 2; ++nt) acc[fi][nt] = (f4v){0.f,0.f,0.f,0.f};
    #pragma unroll
    for (int s = 0; s < KS; ++s){
      const s8v a0 = *(const s8v*)&bufH[HIXBASE(s, quad) + lq*8];
      const s8v a1 = *(const s8v*)&bufH[HIXBASE(s, quad) + (16 + lq)*8];
      #pragma unroll
      for (int fi = 0; fi < 5; ++fi){
        if (fi == 4 && wv != 3) break;
        const int f = (fi == 4) ? 16 : fi*4 + wv;
        const s8v bF = *(const s8v*)&WP[((f*KS + s)*64 + l)*8];
        acc[fi][0] = __builtin_amdgcn_mfma_f32_16x16x32_bf16(a0, bF, acc[fi][0], 0,0,0);
        acc[fi][1] = __builtin_amdgcn_mfma_f32_16x16x32_bf16(a1, bF, acc[fi][1], 0,0,0);
      }
    }
    #pragma unroll
    for (int fi = 0; fi < 5; ++fi){
      if (fi == 4 && (wv != 3 || lq >= 8)) break;  // score cols 8..15 structural zeros (rows 264+ OOB)
      const int f = (fi == 4) ? 16 : fi*4 + wv;
      #pragma unroll
      for (int nt = 0; nt < 2; ++nt){
        uint2 p;
        p.x = pk2(acc[fi][nt][0], acc[fi][nt][1]);
        p.y = pk2(acc[fi][nt][2], acc[fi][nt][3]);
        *(uint2*)&whT[(f*16 + lq)*WSTR + nt*16 + quad*4] = p;
      }
    }
  }
  __syncthreads();
  // ---- softmax: thread (g,h,i) -> alphaS row (g*4+h, i), 16 bf16; no max-sub (scores O(1)) ----
  if (t < 128){
    const int g = t >> 6, h = (t >> 4) & 3, i = t & 15;
    const float ed = b2f(whT[(260 + h)*WSTR + g*16 + i]);
    float ev[16];
    #pragma unroll
    for (int c = 0; c < 4; ++c){
      const s4v v = *(const s4v*)&whT[(256 + h)*WSTR + g*16 + c*4];
      ev[c*4+0]=b2f(v[0]); ev[c*4+1]=b2f(v[1]); ev[c*4+2]=b2f(v[2]); ev[c*4+3]=b2f(v[3]);
    }
    const unsigned m = KMASK[i];
    float ssum = 0.f;
    #pragma unroll
    for (int j = 0; j < 16; ++j){
      float e = ed + ev[j];
      e = (e > 0.f) ? e : 0.2f*e;
      const float a = ((m >> j) & 1u) ? __expf(e) : 0.f;
      ev[j] = a; ssum += a;
    }
    const float inv = 1.f / ssum;
    unsigned* row = (unsigned*)&alphaS[((g*4 + h)*16 + i)*AP];
    #pragma unroll
    for (int c = 0; c < 8; ++c)
      row[c] = pk2(ev[2*c]*inv, ev[2*c+1]*inv);
  }
  __syncthreads();
  // ---- aggregation: B-operand built in regs (zero half selected by quad vs g) ----
  if constexpr (!MEAN){
    const int h = wv;
    union { s8v v; unsigned u[4]; } B[2];
    #pragma unroll
    for (int g = 0; g < 2; ++g){
      const unsigned* ar = (const unsigned*)&alphaS[((g*4 + h)*16 + lq)*AP + (quad & 1)*8];
      const bool act = ((quad >> 1) == g);
      #pragma unroll
      for (int c = 0; c < 4; ++c) B[g].u[c] = act ? ar[c] : 0u;
    }
    #pragma unroll
    for (int ct = 0; ct < 4; ++ct){
      const s8v a = *(const s8v*)&whT[(h*64 + ct*16 + lq)*WSTR + quad*8];
      const int sf = h*2 + (ct >> 1);              // (f0>>5)
      const int qf = (ct & 1)*2 + (quad >> 1);     // (f0>>3)&3
      const int jf = (quad & 1)*4;                 // f0&7
      const int f0 = h*64 + ct*16 + quad*4;
      const float4 bb = *(const float4*)&bbias[f0];
      #pragma unroll
      for (int g = 0; g < 2; ++g){
        f4v d = (f4v){0.f,0.f,0.f,0.f};
        d = __builtin_amdgcn_mfma_f32_16x16x32_bf16(a, B[g].v, d, 0,0,0);
        uint2 p;
        p.x = pk2(fmaxf(d[0] + bb.x, 0.f), fmaxf(d[1] + bb.y, 0.f));
        p.y = pk2(fmaxf(d[2] + bb.z, 0.f), fmaxf(d[3] + bb.w, 0.f));
        *(uint2*)&bufH[HIXBASE(sf, qf) + (g*16 + lq)*8 + jf] = p;
      }
    }
  } else {
    const int g = wv >> 1;
    union { s8v v; unsigned u[4]; } B[4];
    #pragma unroll
    for (int h = 0; h < 4; ++h){
      const unsigned* ar = (const unsigned*)&alphaS[((g*4 + h)*16 + lq)*AP + (quad & 1)*8];
      const bool act = ((quad >> 1) == g);
      #pragma unroll
      for (int c = 0; c < 4; ++c) B[h].u[c] = act ? ar[c] : 0u;
    }
    #pragma unroll
    for (int cc = 0; cc < 2; ++cc){
      const int ct = (wv & 1)*2 + cc;
      f4v d = (f4v){0.f,0.f,0.f,0.f};
      #pragma unroll
      for (int h = 0; h < 4; ++h){
        const s8v a = *(const s8v*)&whT[(h*64 + ct*16 + lq)*WSTR + quad*8];
        d = __builtin_amdgcn_mfma_f32_16x16x32_bf16(a, B[h].v, d, 0,0,0);
      }
      #pragma unroll
      for (int s = 1; s < 16; s <<= 1){
        d[0] += __shfl_xor(d[0], s, 64); d[1] += __shfl_xor(d[1], s, 64);
        d[2] += __shfl_xor(d[2], s, 64); d[3] += __shfl_xor(d[3], s, 64);
      }
      if (lq == 0){
        const int f0 = ct*16 + quad*4;
        const float4 bb = *(const float4*)&bbias[f0];
        float4 gv;
        gv.x = d[0]*(1.f/64.f) + bb.x; gv.y = d[1]*(1.f/64.f) + bb.y;
        gv.z = d[2]*(1.f/64.f) + bb.z; gv.w = d[3]*(1.f/64.f) + bb.w;
        *(float4*)&gsm[g*64 + f0] = gv;
      }
    }
  }
}

__global__ __launch_bounds__(256, 4) void gat_main(
  const float* __restrict__ x,
  const short* __restrict__ WPin, const float* __restrict__ b_in,
  const short* __restrict__ WP0,  const float* __restrict__ bb0,
  const short* __restrict__ WP1,  const float* __restrict__ bb1,
  const short* __restrict__ WP2,  const float* __restrict__ bb2,
  const float* __restrict__ w1,   const float* __restrict__ b1,
  const float* __restrict__ lng,  const float* __restrict__ lnb,
  const float* __restrict__ w2,   const float* __restrict__ b2,
  float* __restrict__ out)
{
  // Deterministic single-carve LDS: 8192 + 9504 + 2560 = 20,256 shorts = 40,512 B -> 4 blocks/CU.
  __shared__ __align__(16) short smem[8*4*32*8 + 264*WSTR + 8*16*AP];
  short* bufH   = smem;                        // fragment-major [8 s][4 quad][32 node][8]
  short* whT    = smem + 8192;                 // [264][WSTR]
  short* alphaS = smem + 8192 + 264*WSTR;      // [8][16][AP]
  short* h0   = whT;                           // [32][40] staging alias (dead before whT written)
  float* gsm  = (float*)bufH;                  // [128] tail alias (bufH dead after last GEMM)
  float* ylds = gsm + 128;                     // [256]
  float* red  = ylds + 256;                    // [8]
  constexpr int H0S = 40;

  const int b = blockIdx.x;
  const int t = threadIdx.x;
  const int l = t & 63, wv = t >> 6, lq = l & 15, quad = l >> 4;

  // stage x: h0[node][ch], zero-pad ch 16..31
  {
    const float2 v = *(const float2*)&x[b*512 + 2*t];
    const int i0 = 2*t;
    const int g = i0 >> 8, c = (i0 >> 4) & 15, n = i0 & 15;
    h0[(g*16 + n)*H0S + c]     = f2b(v.x);
    h0[(g*16 + n + 1)*H0S + c] = f2b(v.y);
    const int r = t >> 3, cc = 16 + 2*(t & 7);
    h0[r*H0S + cc] = 0; h0[r*H0S + cc + 1] = 0;
  }
  __syncthreads();

  // h1 = relu(h0 @ w_in + b_in) -> bufH fragment-major, feats 0..63
  {
    const s8v aF  = *(const s8v*)&WPin[(wv*64 + l)*8];
    const s8v b0v = *(const s8v*)&h0[lq*H0S + quad*8];
    const s8v b1v = *(const s8v*)&h0[(16+lq)*H0S + quad*8];
    f4v acc0 = (f4v){0.f,0.f,0.f,0.f}, acc1 = (f4v){0.f,0.f,0.f,0.f};
    acc0 = __builtin_amdgcn_mfma_f32_16x16x32_bf16(aF, b0v, acc0, 0,0,0);
    acc1 = __builtin_amdgcn_mfma_f32_16x16x32_bf16(aF, b1v, acc1, 0,0,0);
    const int f0 = wv*16 + quad*4;
    const float4 bi = *(const float4*)&b_in[f0];
    const int sf = wv >> 1;                      // f0>>5
    const int qf = (wv & 1)*2 + (quad >> 1);     // (f0>>3)&3
    const int jf = (quad & 1)*4;                 // f0&7
    uint2 p0, p1;
    p0.x = pk2(fmaxf(acc0[0]+bi.x,0.f), fmaxf(acc0[1]+bi.y,0.f));
    p0.y = pk2(fmaxf(acc0[2]+bi.z,0.f), fmaxf(acc0[3]+bi.w,0.f));
    p1.x = pk2(fmaxf(acc1[0]+bi.x,0.f), fmaxf(acc1[1]+bi.y,0.f));
    p1.y = pk2(fmaxf(acc1[2]+bi.z,0.f), fmaxf(acc1[3]+bi.w,0.f));
    *(uint2*)&bufH[HIXBASE(sf, qf) + lq*8 + jf]        = p0;
    *(uint2*)&bufH[HIXBASE(sf, qf) + (16 + lq)*8 + jf] = p1;
  }
  __syncthreads();

  gat_layer<2, false>(bufH, whT, alphaS, WP0, bb0, gsm, t);
  __syncthreads();
  gat_layer<8, false>(bufH, whT, alphaS, WP1, bb1, gsm, t);
  __syncthreads();
  gat_layer<8, true >(bufH, whT, alphaS, WP2, bb2, gsm, t);
  __syncthreads();

  // ---- MLP tail (fp32): y = g@w1+b1, LN, relu, @w2+b2 ----
  const int gg = t >> 7, o = t & 127;
  float yv = b1[o];
  #pragma unroll 8
  for (int k = 0; k < 64; ++k) yv += gsm[gg*64 + k] * w1[k*128 + o];
  float s1 = yv, s2 = yv*yv;
  #pragma unroll
  for (int s = 1; s < 64; s <<= 1){ s1 += __shfl_xor(s1, s, 64); s2 += __shfl_xor(s2, s, 64); }
  if ((t & 63) == 0){ red[(t>>6)*2] = s1; red[(t>>6)*2 + 1] = s2; }
  __syncthreads();
  {
    const float S1 = red[4*gg] + red[4*gg+2], S2 = red[4*gg+1] + red[4*gg+3];
    const float mu  = S1 * (1.f/128.f);
    const float var = S2 * (1.f/128.f) - mu*mu;
    const float yn  = (yv - mu) * rsqrtf(var + 1e-5f) * lng[o] + lnb[o];
    ylds[gg*128 + o] = fmaxf(yn, 0.f);
  }
  __syncthreads();
  float a0 = b2[t], a1 = b2[t];
  #pragma unroll 4
  for (int k = 0; k < 128; ++k){
    const float wv2 = w2[k*256 + t];
    a0 += ylds[k]*wv2; a1 += ylds[128 + k]*wv2;
  }
  out[(b*2 + 0)*256 + t] = a0;
  out[(b*2 + 1)*256 + t] = a1;
}

extern "C" void kernel_launch(void* const* d_in, const int* in_sizes, int n_in,
                              void* d_out, int out_size, void* d_ws, size_t ws_size,
                              hipStream_t stream){
  const float* x    = (const float*)d_in[0];
  const float* w_in = (const float*)d_in[1];
  const float* b_in = (const float*)d_in[2];
  const float* W0   = (const float*)d_in[3];
  const float* as0  = (const float*)d_in[4];
  const float* ad0  = (const float*)d_in[5];
  const float* bb0  = (const float*)d_in[6];
  const float* W1   = (const float*)d_in[7];
  const float* as1  = (const float*)d_in[8];
  const float* ad1  = (const float*)d_in[9];
  const float* bb1  = (const float*)d_in[10];
  const float* W2   = (const float*)d_in[11];
  const float* as2  = (const float*)d_in[12];
  const float* ad2  = (const float*)d_in[13];
  const float* bb2  = (const float*)d_in[14];
  const float* w1   = (const float*)d_in[15];
  const float* b1   = (const float*)d_in[16];
  const float* lng  = (const float*)d_in[17];
  const float* lnb  = (const float*)d_in[18];
  const float* w2   = (const float*)d_in[19];
  const float* b2   = (const float*)d_in[20];
  const int B = in_sizes[0] / 256;

  short* ws = (short*)d_ws;
  const short* WPin = ws;
  const short* WP0  = ws + 2048;
  const short* WP1  = ws + 2048 + 17408;
  const short* WP2  = ws + 2048 + 17408 + 69632;   // ends at 158,720 shorts = 317,440 B (validated)

  prep_all<<<217, 256, 0, stream>>>(W0, as0, ad0, W1, as1, ad1, W2, as2, ad2,
                                    w_in, ws);
  gat_main<<<B/2, 256, 0, stream>>>(x, WPin, b_in, WP0, bb0, WP1, bb1, WP2, bb2,
                                    w1, b1, lng, lnb, w2, b2, (float*)d_out);
}